// Round 7
// baseline (218.826 us; speedup 1.0000x reference)
//
#include <hip/hip_runtime.h>
#include <hip/hip_bf16.h>

// Problem dims
#define B_  2
#define C_  256
#define N_  4096
#define R_  8
#define G_  4
#define CG_ 64

typedef __attribute__((ext_vector_type(8))) short short8;
typedef __attribute__((ext_vector_type(4))) float f32x4;

#define MFMA16(a, b, c) __builtin_amdgcn_mfma_f32_16x16x32_bf16((a), (b), (c), 0, 0, 0)
#define EXP2F(x) __builtin_amdgcn_exp2f(x)
#define LOG2E 1.44269504088896f

__device__ inline unsigned int pk2(float a, float b) {
    union { __hip_bfloat162 h; unsigned int u; } cv;
    cv.h = __float22bfloat162_rn(float2{a, b});
    return cv.u;
}
__device__ inline unsigned short f2bf(float f) {
    union { __hip_bfloat16 h; unsigned short u; } cv;
    cv.h = __float2bfloat16(f);
    return cv.u;
}

// Workspace (ushort units unless noted). All hot data in MFMA fragment order
// [tile][lane 64][8 bf16] -> every hot load is a coalesced 1KB dwordx4.
//  qF  [db 4][nt 256][64][8]  (log2e folded; lanes>=16 zero)
//  kF  [db 4][mt 256][64][8]  (lanes>=16 zero)
//  VF  [db 4][ct 16][nc 128][64][8]  V frags (bias applied)
//  wqkF [s 2][kc 8][64][8]          proj weight frags (q rows *log2e)
//  wvF  [s 2][g 4][ocb 4][kc2 2][64][8]  conv weight frags
//  l2z f32 [db 4][n 4096] = -log2(Z)
#define QF_OFF   0
#define KF_OFF   524288
#define VF_OFF   1048576
#define WQKF_OFF 5242880
#define WVF_OFF  5251072
#define L2Z_OFFF 2641920        // float index (byte 10567680)
// total ~10.6 MB

// ---------------------------------------------------------------------------
// Kernel 0: pack + swizzle weights into fragment order. grid(2) -> s.
// ---------------------------------------------------------------------------
__global__ __launch_bounds__(256) void wpack(
    const float* __restrict__ qLw, const float* __restrict__ kLw,
    const float* __restrict__ vLw,
    const float* __restrict__ qUw, const float* __restrict__ kUw,
    const float* __restrict__ vUw,
    unsigned short* __restrict__ wsu)
{
    const int s = blockIdx.x;
    const float* wq = s ? qUw : qLw;
    const float* wk = s ? kUw : kLw;
    const float* wv = s ? vUw : vLw;

    // wqkF: A[row=o=lane&15][k = kc*32 + (lane>>4)*8 + j]
    for (int i = threadIdx.x; i < 8 * 512; i += 256) {
        const int kc = i >> 9, l = (i >> 3) & 63, j = i & 7;
        const int o = l & 15, c = kc * 32 + (l >> 4) * 8 + j;
        const float v = (o < 8) ? wq[o * C_ + c] * LOG2E : wk[(o - 8) * C_ + c];
        wsu[WQKF_OFF + s * 4096 + i] = f2bf(v);
    }
    // wvF: A[row=oc_local=lane&15][k = kc2*32 + (lane>>4)*8 + j]
    for (int i = threadIdx.x; i < 16384; i += 256) {
        const int g = i >> 12, r1 = i & 4095;
        const int ocb = r1 >> 10, r2 = r1 & 1023;
        const int kc2 = r2 >> 9, l = (r2 >> 3) & 63, j = r2 & 7;
        const int oc = ocb * 16 + (l & 15), ic = kc2 * 32 + (l >> 4) * 8 + j;
        wsu[WVF_OFF + s * 16384 + i] = f2bf(wv[g * (CG_ * CG_) + oc * CG_ + ic]);
    }
}

// ---------------------------------------------------------------------------
// Kernel 1: fused proj + grouped conv -> frag-swizzled qF/kF/VF.
// Coalesced x reads (8 dense float4/thread), fp32 LDS transpose, pre-packed
// weight frags. grid(128 n-strips of 32, 1, 4 z=s*2+b), block 256 (4 waves).
// Waves: ncl=w&1 (n 16-half), gh=w>>1. gh0: proj + groups 0,1; gh1: g2,3.
// ---------------------------------------------------------------------------
#define XSTR 260   // xsf row stride (floats): 1040B, 16B-aligned rows

__global__ __launch_bounds__(256) void fused_pre(
    const float* __restrict__ fL, const float* __restrict__ fU,
    const float* __restrict__ qLb, const float* __restrict__ kLb,
    const float* __restrict__ vLb,
    const float* __restrict__ qUb, const float* __restrict__ kUb,
    const float* __restrict__ vUb,
    unsigned short* __restrict__ wsu)
{
    const int s   = blockIdx.z >> 1;
    const int b   = blockIdx.z & 1;
    const int nc0 = blockIdx.x;        // 32-n strip index
    const int n0  = nc0 * 32;
    const int t   = threadIdx.x;

    const float* x  = (s ? fU : fL) + (size_t)b * C_ * N_;
    const float* bq = s ? qUb : qLb;
    const float* bk = s ? kUb : kLb;
    const float* bv = s ? vUb : vLb;
    const int dq = s, dk = 1 - s, dv = 1 - s;

    __shared__ __align__(16) float xsf[32 * XSTR];          // [n 32][c 256]
    __shared__ __align__(16) unsigned short vtmp[256 * 48]; // [c 256][n 32]
    __shared__ __align__(16) float qtmp[2][16][17];

    const int w  = t >> 6;
    const int l  = t & 63;
    const int lm = l & 15;
    const int q  = l >> 4;

    // ---- stage x: dense coalesced reads, transpose into LDS fp32 ----
    {
        const int cr  = w * 8 + (l >> 3);   // c row within 32-chunk
        const int ncl_ = (l & 7) * 4;       // n col
        float4 xv[8];
#pragma unroll
        for (int it = 0; it < 8; it++)
            xv[it] = *reinterpret_cast<const float4*>(
                x + (size_t)(it * 32 + cr) * N_ + n0 + ncl_);
#pragma unroll
        for (int it = 0; it < 8; it++) {
            const int c = it * 32 + cr;
            xsf[(ncl_ + 0) * XSTR + c] = xv[it].x;
            xsf[(ncl_ + 1) * XSTR + c] = xv[it].y;
            xsf[(ncl_ + 2) * XSTR + c] = xv[it].z;
            xsf[(ncl_ + 3) * XSTR + c] = xv[it].w;
        }
    }
    __syncthreads();

    const int ncl = w & 1;
    const int gh  = w >> 1;
    const int nrow = ncl * 16 + lm;
    const int n = n0 + nrow;

    // ---- B-frags: B[col=n=lm][k=c=kc*32+q*8+j] from xsf (pack fp32->bf16) ----
    short8 bf[8];
    {
        const float* xr = xsf + nrow * XSTR + q * 8;
        const int kclo = (gh == 0) ? 0 : 4;
#pragma unroll
        for (int kc = 0; kc < 8; kc++) {
            if (kc < kclo) continue;
            const float4 f0 = *reinterpret_cast<const float4*>(xr + kc * 32);
            const float4 f1 = *reinterpret_cast<const float4*>(xr + kc * 32 + 4);
            union { unsigned int u[4]; short8 v; } bb;
            bb.u[0] = pk2(f0.x, f0.y); bb.u[1] = pk2(f0.z, f0.w);
            bb.u[2] = pk2(f1.x, f1.y); bb.u[3] = pk2(f1.z, f1.w);
            bf[kc] = bb.v;
        }
    }

    // ---- proj (gh==0 waves): rows 0-7 q (log2e-scaled), 8-15 k ----
    if (gh == 0) {
        const unsigned short* wb = wsu + WQKF_OFF + s * 4096;
        f32x4 pa = {0.f, 0.f, 0.f, 0.f};
#pragma unroll
        for (int kc = 0; kc < 8; kc++) {
            const short8 af = *reinterpret_cast<const short8*>(wb + kc * 512 + l * 8);
            pa = MFMA16(af, bf[kc], pa);
        }
        // bias, transpose via same-wave LDS bounce, frag-order store
#pragma unroll
        for (int r = 0; r < 4; r++) {
            const int oo = q * 4 + r;
            qtmp[w][oo][lm] = pa[r] + ((q < 2) ? bq[oo] * LOG2E : bk[oo - 8]);
        }
        const int nt = nc0 * 2 + w;      // 16-n tile index
        uint4 pq = {0u, 0u, 0u, 0u}, pk = {0u, 0u, 0u, 0u};
        if (q == 0) {
            float aq[8], ak[8];
#pragma unroll
            for (int o2 = 0; o2 < 8; o2++) { aq[o2] = qtmp[w][o2][lm]; ak[o2] = qtmp[w][8 + o2][lm]; }
            pq.x = pk2(aq[0], aq[1]); pq.y = pk2(aq[2], aq[3]);
            pq.z = pk2(aq[4], aq[5]); pq.w = pk2(aq[6], aq[7]);
            pk.x = pk2(ak[0], ak[1]); pk.y = pk2(ak[2], ak[3]);
            pk.z = pk2(ak[4], ak[5]); pk.w = pk2(ak[6], ak[7]);
        }
        *reinterpret_cast<uint4*>(wsu + QF_OFF + ((size_t)(dq * B_ + b) * 256 + nt) * 512 + l * 8) = pq;
        *reinterpret_cast<uint4*>(wsu + KF_OFF + ((size_t)(dk * B_ + b) * 256 + nt) * 512 + l * 8) = pk;
    }

    // ---- grouped conv: this wave's two groups -> vtmp [c][n] ----
    {
        const unsigned short* vb = wsu + WVF_OFF + s * 16384;
#pragma unroll
        for (int gi = 0; gi < 2; gi++) {
            const int g = gh * 2 + gi;
#pragma unroll
            for (int ocb = 0; ocb < 4; ocb++) {
                f32x4 ca = {0.f, 0.f, 0.f, 0.f};
#pragma unroll
                for (int kc2 = 0; kc2 < 2; kc2++) {
                    const short8 af = *reinterpret_cast<const short8*>(
                        vb + (((g * 4 + ocb) * 2 + kc2) * 512) + l * 8);
                    ca = MFMA16(af, bf[g * 2 + kc2], ca);
                }
#pragma unroll
                for (int r = 0; r < 4; r++) {
                    const int c = g * 64 + ocb * 16 + q * 4 + r;
                    vtmp[c * 48 + ncl * 16 + lm] = f2bf(ca[r] + bv[c]);
                }
            }
        }
    }
    __syncthreads();

    // ---- emit VF frags: A[row=c_local=lm][k=n_local=q*8+j], coalesced ----
    {
        const int db = dv * B_ + b;
#pragma unroll
        for (int ctl = 0; ctl < 4; ctl++) {
            const int ct = w * 4 + ctl;
            const uint4 v4 = *reinterpret_cast<const uint4*>(vtmp + (ct * 16 + lm) * 48 + q * 8);
            *reinterpret_cast<uint4*>(
                wsu + VF_OFF + ((size_t)(db * 16 + ct) * 128 + nc0) * 512 + l * 8) = v4;
        }
    }
}

// ---------------------------------------------------------------------------
// Kernel 2: l2z[db][n] = -log2( sum_m exp2(s'[n][m]) ), rank-8 padded MFMA.
// grid(128 n-strips of 32, B, 2), block 256; wave w sums m-quarter.
// ---------------------------------------------------------------------------
__global__ __launch_bounds__(256) void zcalc(const unsigned short* __restrict__ wsu,
                                             float* __restrict__ wsf)
{
    const int d   = blockIdx.z;
    const int b   = blockIdx.y;
    const int nc0 = blockIdx.x;
    const int db  = d * B_ + b;
    const int t   = threadIdx.x;
    const int w   = t >> 6;
    const int l   = t & 63;
    const int lm  = l & 15;
    const int q   = l >> 4;

    const unsigned short* qF = wsu + QF_OFF + (size_t)db * 256 * 512;
    const unsigned short* kF = wsu + KF_OFF + (size_t)db * 256 * 512;

    const short8 qf0 = *reinterpret_cast<const short8*>(qF + (size_t)(nc0 * 2 + 0) * 512 + l * 8);
    const short8 qf1 = *reinterpret_cast<const short8*>(qF + (size_t)(nc0 * 2 + 1) * 512 + l * 8);

    const f32x4 zero = {0.f, 0.f, 0.f, 0.f};
    float za0[4] = {0.f, 0.f, 0.f, 0.f};
    float za1[4] = {0.f, 0.f, 0.f, 0.f};

    short8 kc_ = *reinterpret_cast<const short8*>(kF + (size_t)(w * 64) * 512 + l * 8);
    for (int it = 0; it < 64; it++) {
        const int nmt = w * 64 + ((it + 1) & 63);
        const short8 kn = *reinterpret_cast<const short8*>(kF + (size_t)nmt * 512 + l * 8);
        const f32x4 s0 = MFMA16(qf0, kc_, zero);
        const f32x4 s1 = MFMA16(qf1, kc_, zero);
#pragma unroll
        for (int r = 0; r < 4; r++) { za0[r] += EXP2F(s0[r]); za1[r] += EXP2F(s1[r]); }
        kc_ = kn;
    }

#pragma unroll
    for (int r = 0; r < 4; r++) {
        za0[r] += __shfl_xor(za0[r], 1); za0[r] += __shfl_xor(za0[r], 2);
        za0[r] += __shfl_xor(za0[r], 4); za0[r] += __shfl_xor(za0[r], 8);
        za1[r] += __shfl_xor(za1[r], 1); za1[r] += __shfl_xor(za1[r], 2);
        za1[r] += __shfl_xor(za1[r], 4); za1[r] += __shfl_xor(za1[r], 8);
    }

    __shared__ __align__(16) float zred[4][2][16];
    if (lm == 0) {
        *reinterpret_cast<float4*>(&zred[w][0][q * 4]) = float4{za0[0], za0[1], za0[2], za0[3]};
        *reinterpret_cast<float4*>(&zred[w][1][q * 4]) = float4{za1[0], za1[1], za1[2], za1[3]};
    }
    __syncthreads();
    if (t < 32) {
        const float Z = zred[0][t >> 4][t & 15] + zred[1][t >> 4][t & 15]
                      + zred[2][t >> 4][t & 15] + zred[3][t >> 4][t & 15];
        wsf[L2Z_OFFF + (size_t)db * N_ + nc0 * 32 + t] = -__log2f(Z);
    }
}

// ---------------------------------------------------------------------------
// Kernel 3: out = f + beta * V · E.  Block tile 128c(ch) x 64m, full-n loop.
// XCD-aware 1-D grid of 512: xcd=id&7 -> db=xcd>>1, ch=xcd&1; mt=id>>3.
// Each XCD's L2 holds exactly one (db,ch) working set (~2MB: VF-half + qF/kF).
// Waves (4): wc=w&1 c-64-half, wm=w>>1 m-32-half. Per kstep: wave E-gens its
// 32m x 32n quadrant (4 padded MFMAs, l2z in C-op, 16 exp2) -> 1 barrier
// (dbuf) -> mainm 16 MFMAs. E computed once per block.
// ---------------------------------------------------------------------------
#define ESTR 72

__global__ __launch_bounds__(256) void attn_gemm(
    const float* __restrict__ fL, const float* __restrict__ fU,
    const float* __restrict__ betap,
    const unsigned short* __restrict__ wsu,
    const float* __restrict__ wsf,
    float* __restrict__ out)
{
    const int id = blockIdx.x;
    const int xcd = id & 7;
    const int db = xcd >> 1;
    const int ch = xcd & 1;
    const int mt = id >> 3;            // 0..63
    const int d  = db >> 1;
    const int b  = db & 1;
    const int t  = threadIdx.x;
    const int w  = t >> 6;
    const int l  = t & 63;
    const int lm = l & 15;
    const int q  = l >> 4;
    const int wc = w & 1;              // c 64-half within 128-c block
    const int wm = w >> 1;             // m 32-half within 64-m block
    const int m0 = mt * 64;

    const unsigned short* qF = wsu + QF_OFF + (size_t)db * 256 * 512;
    const unsigned short* kF = wsu + KF_OFF + (size_t)db * 256 * 512;
    const unsigned short* VF = wsu + VF_OFF + (size_t)db * 16 * 128 * 512;
    const float* l2z = wsf + L2Z_OFFF + (size_t)db * N_;
    const float* f = ((d == 0) ? fL : fU) + (size_t)b * C_ * N_;
    float*       o = out + (size_t)db * C_ * N_;

    __shared__ __align__(16) unsigned short Es[2][64 * ESTR];  // [m 64][n 64]

    // persistent k-frags: this wave's m-32-half -> 2 m-tiles
    short8 kf[2];
#pragma unroll
    for (int mb = 0; mb < 2; mb++)
        kf[mb] = *reinterpret_cast<const short8*>(
            kF + (size_t)(mt * 4 + wm * 2 + mb) * 512 + l * 8);

    // A-frag bases: wave wc owns c-tiles ch*8 + wc*4 + cb
    const unsigned short* Ab[4];
#pragma unroll
    for (int cb = 0; cb < 4; cb++)
        Ab[cb] = VF + (size_t)(ch * 8 + wc * 4 + cb) * 128 * 512 + l * 8;

    f32x4 acc[4][2];
#pragma unroll
    for (int cb = 0; cb < 4; cb++)
#pragma unroll
        for (int mb = 0; mb < 2; mb++) acc[cb][mb] = f32x4{0.f, 0.f, 0.f, 0.f};

    short8 A0[8], A1[8], q0[2], q1[2];
    f32x4  z0[2], z1[2];

    auto loadA = [&](short8* A, int i) {
        const int nc = (i & 63) * 2;
#pragma unroll
        for (int cb = 0; cb < 4; cb++)
#pragma unroll
            for (int kc = 0; kc < 2; kc++)
                A[cb * 2 + kc] = *reinterpret_cast<const short8*>(
                    Ab[cb] + (size_t)(nc + kc) * 512);
    };
    auto loadQZ = [&](short8* qA, f32x4* zf, int i) {
        const int ii = i & 63;
#pragma unroll
        for (int nc = 0; nc < 2; nc++) {
            qA[nc] = *reinterpret_cast<const short8*>(
                qF + (size_t)(ii * 4 + wc * 2 + nc) * 512 + l * 8);
            zf[nc] = *reinterpret_cast<const f32x4*>(
                l2z + ii * 64 + wc * 32 + nc * 16 + q * 4);
        }
    };
    // E-gen: wave quadrant = m rows wm*32..+31, n cols wc*32..+31
    auto egen = [&](const short8* qA, const f32x4* zf, unsigned short* Eb) {
#pragma unroll
        for (int mb = 0; mb < 2; mb++)
#pragma unroll
            for (int nc = 0; nc < 2; nc++) {
                const f32x4 sv = MFMA16(qA[nc], kf[mb], zf[nc]);
                uint2 p;
                p.x = pk2(EXP2F(sv[0]), EXP2F(sv[1]));
                p.y = pk2(EXP2F(sv[2]), EXP2F(sv[3]));
                *reinterpret_cast<uint2*>(
                    Eb + (wm * 32 + mb * 16 + lm) * ESTR + wc * 32 + nc * 16 + q * 4) = p;
            }
    };
    auto mainm = [&](const short8* A, const unsigned short* Eb) {
        short8 Bf[2][2];
#pragma unroll
        for (int mb = 0; mb < 2; mb++)
#pragma unroll
            for (int kc = 0; kc < 2; kc++)
                Bf[mb][kc] = *reinterpret_cast<const short8*>(
                    Eb + (wm * 32 + mb * 16 + lm) * ESTR + kc * 32 + q * 8);
#pragma unroll
        for (int kc = 0; kc < 2; kc++)
#pragma unroll
            for (int cb = 0; cb < 4; cb++)
#pragma unroll
                for (int mb = 0; mb < 2; mb++)
                    acc[cb][mb] = MFMA16(A[cb * 2 + kc], Bf[mb][kc], acc[cb][mb]);
    };

    loadA(A0, 0);
    loadQZ(q0, z0, 0);

    for (int i = 0; i < 64; i += 2) {
        egen(q0, z0, Es[0]);
        __syncthreads();
        loadA(A1, i + 1); loadQZ(q1, z1, i + 1);
        mainm(A0, Es[0]);

        egen(q1, z1, Es[1]);
        __syncthreads();
        loadA(A0, i + 2); loadQZ(q0, z0, i + 2);
        mainm(A1, Es[1]);
    }

    // epilogue: out = f + beta * acc  (D rows c = q*4+r, col m = lm)
    const float beta = *betap;
#pragma unroll
    for (int cb = 0; cb < 4; cb++) {
#pragma unroll
        for (int mb = 0; mb < 2; mb++) {
            const int c = ch * 128 + wc * 64 + cb * 16 + q * 4;
            const int m = m0 + wm * 32 + mb * 16 + lm;
#pragma unroll
            for (int r = 0; r < 4; r++) {
                const size_t off = (size_t)(c + r) * N_ + m;
                o[off] = f[off] + beta * acc[cb][mb][r];
            }
        }
    }
}

// ---------------------------------------------------------------------------
extern "C" void kernel_launch(void* const* d_in, const int* in_sizes, int n_in,
                              void* d_out, int out_size, void* d_ws, size_t ws_size,
                              hipStream_t stream)
{
    const float* fL   = (const float*)d_in[0];
    const float* fU   = (const float*)d_in[1];
    const float* qL_w = (const float*)d_in[2];
    const float* qL_b = (const float*)d_in[3];
    const float* kU_w = (const float*)d_in[4];
    const float* kU_b = (const float*)d_in[5];
    const float* vU_w = (const float*)d_in[6];
    const float* vU_b = (const float*)d_in[7];
    const float* qU_w = (const float*)d_in[8];
    const float* qU_b = (const float*)d_in[9];
    const float* kL_w = (const float*)d_in[10];
    const float* kL_b = (const float*)d_in[11];
    const float* vL_w = (const float*)d_in[12];
    const float* vL_b = (const float*)d_in[13];
    const float* beta = (const float*)d_in[14];

    unsigned short* wsu  = (unsigned short*)d_ws;
    float*          wsf  = (float*)d_ws;
    float*          outf = (float*)d_out;

    wpack<<<dim3(2), 256, 0, stream>>>(qL_w, kL_w, vL_w, qU_w, kU_w, vU_w, wsu);

    fused_pre<<<dim3(128, 1, 4), 256, 0, stream>>>(
        fL, fU, qL_b, kL_b, vL_b, qU_b, kU_b, vU_b, wsu);

    zcalc<<<dim3(128, B_, 2), 256, 0, stream>>>(wsu, wsf);

    attn_gemm<<<dim3(512), 256, 0, stream>>>(
        fL, fU, beta, wsu, wsf, outf);
}

// Round 8
// 185.507 us; speedup vs baseline: 1.1796x; 1.1796x over previous
//
#include <hip/hip_runtime.h>
#include <hip/hip_bf16.h>

// Problem dims
#define B_  2
#define C_  256
#define N_  4096
#define R_  8
#define G_  4
#define CG_ 64

typedef __attribute__((ext_vector_type(8))) short short8;
typedef __attribute__((ext_vector_type(4))) float f32x4;

#define MFMA16(a, b, c) __builtin_amdgcn_mfma_f32_16x16x32_bf16((a), (b), (c), 0, 0, 0)
#define EXP2F(x) __builtin_amdgcn_exp2f(x)
#define LOG2E 1.44269504088896f

__device__ inline unsigned int pk2(float a, float b) {
    union { __hip_bfloat162 h; unsigned int u; } cv;
    cv.h = __float22bfloat162_rn(float2{a, b});
    return cv.u;
}
__device__ inline unsigned short f2bf(float f) {
    union { __hip_bfloat16 h; unsigned short u; } cv;
    cv.h = __float2bfloat16(f);
    return cv.u;
}

// Workspace (ushort units unless noted). All hot data in MFMA fragment order
// [tile][lane 64][8 bf16] -> every hot load is a coalesced 1KB dwordx4.
//  qF  [db 4][nt 256][64][8]  (log2e folded; lanes>=16 zero)
//  kF  [db 4][mt 256][64][8]  (lanes>=16 zero)
//  VF  [db 4][ct 16][nc 128][64][8]  V frags (bias applied)
//  l2z f32 [db 4][n 4096] = -log2(Z)
#define QF_OFF   0
#define KF_OFF   524288
#define VF_OFF   1048576
#define L2Z_OFFF 2621440        // float index (byte 10485760)
// total ~10.6 MB

// ---------------------------------------------------------------------------
// Kernel 1: fused proj + grouped conv -> frag-swizzled qF/kF/VF.
// Coalesced x reads (8 dense float4/thread), fp32 LDS transpose, weights
// packed inline (L2-cached fp32 reads + pk2).
// grid(128 n-strips of 32, 1, 4 z=s*2+b), block 256 (4 waves).
// Waves: ncl=w&1 (n 16-half), gh=w>>1. gh0: proj + groups 0,1; gh1: g2,3.
// ---------------------------------------------------------------------------
#define XSTR 260   // xsf row stride (floats)
#define VTS  56    // vtmp row stride (shorts): 112B = 16B-aligned, conflict-light

__global__ __launch_bounds__(256) void fused_pre(
    const float* __restrict__ fL, const float* __restrict__ fU,
    const float* __restrict__ qLw, const float* __restrict__ qLb,
    const float* __restrict__ kLw, const float* __restrict__ kLb,
    const float* __restrict__ vLw, const float* __restrict__ vLb,
    const float* __restrict__ qUw, const float* __restrict__ qUb,
    const float* __restrict__ kUw, const float* __restrict__ kUb,
    const float* __restrict__ vUw, const float* __restrict__ vUb,
    unsigned short* __restrict__ wsu)
{
    const int s   = blockIdx.z >> 1;
    const int b   = blockIdx.z & 1;
    const int nc0 = blockIdx.x;        // 32-n strip index
    const int n0  = nc0 * 32;
    const int t   = threadIdx.x;

    const float* x  = (s ? fU : fL) + (size_t)b * C_ * N_;
    const float* wq = s ? qUw : qLw;
    const float* bq = s ? qUb : qLb;
    const float* wk = s ? kUw : kLw;
    const float* bk = s ? kUb : kLb;
    const float* wv = s ? vUw : vLw;
    const float* bv = s ? vUb : vLb;
    const int dq = s, dk = 1 - s, dv = 1 - s;

    __shared__ __align__(16) float xsf[32 * XSTR];           // [n 32][c 256]
    __shared__ __align__(16) unsigned short vtmp[256 * VTS]; // [c 256][n 32]
    __shared__ __align__(16) float qtmp[2][16][17];

    const int w  = t >> 6;
    const int l  = t & 63;
    const int lm = l & 15;
    const int q  = l >> 4;

    // ---- stage x: dense coalesced reads, transpose into LDS fp32 ----
    {
        const int cr   = w * 8 + (l >> 3);  // c row within 32-chunk
        const int ncl_ = (l & 7) * 4;       // n col
        float4 xv[8];
#pragma unroll
        for (int it = 0; it < 8; it++)
            xv[it] = *reinterpret_cast<const float4*>(
                x + (size_t)(it * 32 + cr) * N_ + n0 + ncl_);
#pragma unroll
        for (int it = 0; it < 8; it++) {
            const int c = it * 32 + cr;
            xsf[(ncl_ + 0) * XSTR + c] = xv[it].x;
            xsf[(ncl_ + 1) * XSTR + c] = xv[it].y;
            xsf[(ncl_ + 2) * XSTR + c] = xv[it].z;
            xsf[(ncl_ + 3) * XSTR + c] = xv[it].w;
        }
    }
    __syncthreads();

    const int ncl = w & 1;
    const int gh  = w >> 1;
    const int nrow = ncl * 16 + lm;
    const int n = n0 + nrow;

    // ---- B-frags: B[col=n=lm][k=c=kc*32+q*8+j] from xsf (pack fp32->bf16) ----
    short8 bf[8];
    {
        const float* xr = xsf + nrow * XSTR + q * 8;
        const int kclo = (gh == 0) ? 0 : 4;
#pragma unroll
        for (int kc = 0; kc < 8; kc++) {
            if (kc < kclo) continue;
            const float4 f0 = *reinterpret_cast<const float4*>(xr + kc * 32);
            const float4 f1 = *reinterpret_cast<const float4*>(xr + kc * 32 + 4);
            union { unsigned int u[4]; short8 v; } bb;
            bb.u[0] = pk2(f0.x, f0.y); bb.u[1] = pk2(f0.z, f0.w);
            bb.u[2] = pk2(f1.x, f1.y); bb.u[3] = pk2(f1.z, f1.w);
            bf[kc] = bb.v;
        }
    }

    // ---- proj (gh==0 waves): rows 0-7 q (log2e-scaled), 8-15 k ----
    if (gh == 0) {
        const int o = lm;
        const float* wrow = (o < 8) ? (wq + o * C_) : (wk + (o - 8) * C_);
        const float scl = (o < 8) ? LOG2E : 1.0f;
        f32x4 pa = {0.f, 0.f, 0.f, 0.f};
#pragma unroll
        for (int kc = 0; kc < 8; kc++) {
            const float4 w0 = *reinterpret_cast<const float4*>(wrow + kc * 32 + q * 8);
            const float4 w1 = *reinterpret_cast<const float4*>(wrow + kc * 32 + q * 8 + 4);
            union { unsigned int u[4]; short8 v; } aw;
            aw.u[0] = pk2(w0.x * scl, w0.y * scl);
            aw.u[1] = pk2(w0.z * scl, w0.w * scl);
            aw.u[2] = pk2(w1.x * scl, w1.y * scl);
            aw.u[3] = pk2(w1.z * scl, w1.w * scl);
            pa = MFMA16(aw.v, bf[kc], pa);
        }
        // bias, transpose via same-wave LDS bounce, frag-order store
#pragma unroll
        for (int r = 0; r < 4; r++) {
            const int oo = q * 4 + r;
            qtmp[w][oo][lm] = pa[r] + ((q < 2) ? bq[oo] * LOG2E : bk[oo - 8]);
        }
        const int nt = nc0 * 2 + w;      // 16-n tile index
        uint4 pq = {0u, 0u, 0u, 0u}, pk = {0u, 0u, 0u, 0u};
        if (q == 0) {
            float aq[8], ak[8];
#pragma unroll
            for (int o2 = 0; o2 < 8; o2++) { aq[o2] = qtmp[w][o2][lm]; ak[o2] = qtmp[w][8 + o2][lm]; }
            pq.x = pk2(aq[0], aq[1]); pq.y = pk2(aq[2], aq[3]);
            pq.z = pk2(aq[4], aq[5]); pq.w = pk2(aq[6], aq[7]);
            pk.x = pk2(ak[0], ak[1]); pk.y = pk2(ak[2], ak[3]);
            pk.z = pk2(ak[4], ak[5]); pk.w = pk2(ak[6], ak[7]);
        }
        *reinterpret_cast<uint4*>(wsu + QF_OFF + ((size_t)(dq * B_ + b) * 256 + nt) * 512 + l * 8) = pq;
        *reinterpret_cast<uint4*>(wsu + KF_OFF + ((size_t)(dk * B_ + b) * 256 + nt) * 512 + l * 8) = pk;
    }

    // ---- grouped conv: this wave's two groups -> vtmp [c][n] ----
    {
#pragma unroll
        for (int gi = 0; gi < 2; gi++) {
            const int g = gh * 2 + gi;
#pragma unroll
            for (int ocb = 0; ocb < 4; ocb++) {
                f32x4 ca = {0.f, 0.f, 0.f, 0.f};
#pragma unroll
                for (int kc2 = 0; kc2 < 2; kc2++) {
                    const float* wr = wv + (size_t)g * (CG_ * CG_)
                                    + (ocb * 16 + lm) * CG_ + kc2 * 32 + q * 8;
                    const float4 w0 = *reinterpret_cast<const float4*>(wr);
                    const float4 w1 = *reinterpret_cast<const float4*>(wr + 4);
                    union { unsigned int u[4]; short8 v; } aw;
                    aw.u[0] = pk2(w0.x, w0.y); aw.u[1] = pk2(w0.z, w0.w);
                    aw.u[2] = pk2(w1.x, w1.y); aw.u[3] = pk2(w1.z, w1.w);
                    ca = MFMA16(aw.v, bf[g * 2 + kc2], ca);
                }
#pragma unroll
                for (int r = 0; r < 4; r++) {
                    const int c = g * 64 + ocb * 16 + q * 4 + r;
                    vtmp[c * VTS + ncl * 16 + lm] = f2bf(ca[r] + bv[c]);
                }
            }
        }
    }
    __syncthreads();

    // ---- emit VF frags: A[row=c_local=lm][k=n_local=q*8+j], coalesced ----
    {
        const int db = dv * B_ + b;
#pragma unroll
        for (int ctl = 0; ctl < 4; ctl++) {
            const int ct = w * 4 + ctl;
            const uint4 v4 = *reinterpret_cast<const uint4*>(vtmp + (ct * 16 + lm) * VTS + q * 8);
            *reinterpret_cast<uint4*>(
                wsu + VF_OFF + ((size_t)(db * 16 + ct) * 128 + nc0) * 512 + l * 8) = v4;
        }
    }
}

// ---------------------------------------------------------------------------
// Kernel 2: l2z[db][n] = -log2( sum_m exp2(s'[n][m]) ), rank-8 padded MFMA.
// grid(128 n-strips of 32, B, 2), block 256; wave w sums m-quarter.
// ---------------------------------------------------------------------------
__global__ __launch_bounds__(256) void zcalc(const unsigned short* __restrict__ wsu,
                                             float* __restrict__ wsf)
{
    const int d   = blockIdx.z;
    const int b   = blockIdx.y;
    const int nc0 = blockIdx.x;
    const int db  = d * B_ + b;
    const int t   = threadIdx.x;
    const int w   = t >> 6;
    const int l   = t & 63;
    const int lm  = l & 15;
    const int q   = l >> 4;

    const unsigned short* qF = wsu + QF_OFF + (size_t)db * 256 * 512;
    const unsigned short* kF = wsu + KF_OFF + (size_t)db * 256 * 512;

    const short8 qf0 = *reinterpret_cast<const short8*>(qF + (size_t)(nc0 * 2 + 0) * 512 + l * 8);
    const short8 qf1 = *reinterpret_cast<const short8*>(qF + (size_t)(nc0 * 2 + 1) * 512 + l * 8);

    const f32x4 zero = {0.f, 0.f, 0.f, 0.f};
    float za0[4] = {0.f, 0.f, 0.f, 0.f};
    float za1[4] = {0.f, 0.f, 0.f, 0.f};

    short8 kc_ = *reinterpret_cast<const short8*>(kF + (size_t)(w * 64) * 512 + l * 8);
    for (int it = 0; it < 64; it++) {
        const int nmt = w * 64 + ((it + 1) & 63);
        const short8 kn = *reinterpret_cast<const short8*>(kF + (size_t)nmt * 512 + l * 8);
        const f32x4 s0 = MFMA16(qf0, kc_, zero);
        const f32x4 s1 = MFMA16(qf1, kc_, zero);
#pragma unroll
        for (int r = 0; r < 4; r++) { za0[r] += EXP2F(s0[r]); za1[r] += EXP2F(s1[r]); }
        kc_ = kn;
    }

#pragma unroll
    for (int r = 0; r < 4; r++) {
        za0[r] += __shfl_xor(za0[r], 1); za0[r] += __shfl_xor(za0[r], 2);
        za0[r] += __shfl_xor(za0[r], 4); za0[r] += __shfl_xor(za0[r], 8);
        za1[r] += __shfl_xor(za1[r], 1); za1[r] += __shfl_xor(za1[r], 2);
        za1[r] += __shfl_xor(za1[r], 4); za1[r] += __shfl_xor(za1[r], 8);
    }

    __shared__ __align__(16) float zred[4][2][16];
    if (lm == 0) {
        *reinterpret_cast<float4*>(&zred[w][0][q * 4]) = float4{za0[0], za0[1], za0[2], za0[3]};
        *reinterpret_cast<float4*>(&zred[w][1][q * 4]) = float4{za1[0], za1[1], za1[2], za1[3]};
    }
    __syncthreads();
    if (t < 32) {
        const float Z = zred[0][t >> 4][t & 15] + zred[1][t >> 4][t & 15]
                      + zred[2][t >> 4][t & 15] + zred[3][t >> 4][t & 15];
        wsf[L2Z_OFFF + (size_t)db * N_ + nc0 * 32 + t] = -__log2f(Z);
    }
}

// ---------------------------------------------------------------------------
// Kernel 3: out = f + beta * V · E, E[n,m]=exp2(q·k - log2Z) computed ONCE.
// Block tile 256c x 32m (full C -> zero E duplication), BK=128 -> 32 ksteps,
// ONE barrier per kstep (Es double-buffered). Per kstep: wave w E-gens its
// 32-n slice (4 padded MFMAs, l2z in C-op, 16 exp2) -> barrier -> 8
// ds_read_b128 + 32 main MFMAs. Load schedule: loadA(i+1) issues BEFORE
// egen(i+1) so the barrier's forced vmcnt(0) drain lands exactly at use;
// q/z one kstep ahead with fine-grained vmcnt (used before their barrier).
// grid(128 m-tiles, 1, 4 db) = 512 blocks, 2 blocks/CU.
// ---------------------------------------------------------------------------
#define ESTR 136   // Es row stride (shorts): 272B rows, 16B-aligned

__global__ __launch_bounds__(256) void attn_gemm(
    const float* __restrict__ fL, const float* __restrict__ fU,
    const float* __restrict__ betap,
    const unsigned short* __restrict__ wsu,
    const float* __restrict__ wsf,
    float* __restrict__ out)
{
    const int db = blockIdx.z;
    const int d  = db >> 1;
    const int b  = db & 1;
    const int t  = threadIdx.x;
    const int w  = t >> 6;
    const int l  = t & 63;
    const int lm = l & 15;
    const int q  = l >> 4;
    const int m0 = blockIdx.x * 32;

    const unsigned short* qF = wsu + QF_OFF + (size_t)db * 256 * 512;
    const unsigned short* kF = wsu + KF_OFF + (size_t)db * 256 * 512;
    const unsigned short* VF = wsu + VF_OFF + (size_t)db * 16 * 128 * 512;
    const float* l2z = wsf + L2Z_OFFF + (size_t)db * N_;
    const float* f = ((d == 0) ? fL : fU) + (size_t)b * C_ * N_;
    float*       o = out + (size_t)db * C_ * N_;

    __shared__ __align__(16) unsigned short Es[2][32 * ESTR];  // [m 32][n 128]

    // persistent k-frags (this block's 32 m; zero quads baked into kF)
    short8 kf[2];
#pragma unroll
    for (int mb = 0; mb < 2; mb++)
        kf[mb] = *reinterpret_cast<const short8*>(
            kF + (size_t)(blockIdx.x * 2 + mb) * 512 + l * 8);

    // A-frag bases: wave w owns c-tiles w*4..w*4+3
    const unsigned short* Ab[4];
#pragma unroll
    for (int cb = 0; cb < 4; cb++)
        Ab[cb] = VF + (size_t)(w * 4 + cb) * 128 * 512 + l * 8;

    f32x4 acc[4][2];
#pragma unroll
    for (int cb = 0; cb < 4; cb++)
#pragma unroll
        for (int mb = 0; mb < 2; mb++) acc[cb][mb] = f32x4{0.f, 0.f, 0.f, 0.f};

    short8 A[16];           // single A buffer (16 frags = one BK=128 kstep)
    short8 q0[2], q1[2];
    f32x4  z0[2], z1[2];

    auto loadA = [&](int i) {
        const int nc = (i & 31) * 4;
#pragma unroll
        for (int cb = 0; cb < 4; cb++)
#pragma unroll
            for (int kc = 0; kc < 4; kc++)
                A[cb * 4 + kc] = *reinterpret_cast<const short8*>(
                    Ab[cb] + (size_t)(nc + kc) * 512);
    };
    auto loadQZ = [&](short8* qA, f32x4* zf, int i) {
        const int ii = i & 31;
#pragma unroll
        for (int nc = 0; nc < 2; nc++) {
            qA[nc] = *reinterpret_cast<const short8*>(
                qF + (size_t)(ii * 8 + w * 2 + nc) * 512 + l * 8);
            zf[nc] = *reinterpret_cast<const f32x4*>(
                l2z + ii * 128 + w * 32 + nc * 16 + q * 4);
        }
    };
    // E-gen: wave slice = n cols w*32..+31 over 32 m
    auto egen = [&](const short8* qA, const f32x4* zf, unsigned short* Eb) {
#pragma unroll
        for (int mb = 0; mb < 2; mb++)
#pragma unroll
            for (int nc = 0; nc < 2; nc++) {
                const f32x4 sv = MFMA16(qA[nc], kf[mb], zf[nc]);
                uint2 p;
                p.x = pk2(EXP2F(sv[0]), EXP2F(sv[1]));
                p.y = pk2(EXP2F(sv[2]), EXP2F(sv[3]));
                *reinterpret_cast<uint2*>(
                    Eb + (mb * 16 + lm) * ESTR + w * 32 + nc * 16 + q * 4) = p;
            }
    };
    auto mainm = [&](const unsigned short* Eb) {
#pragma unroll
        for (int kc = 0; kc < 4; kc++) {
            short8 Bf[2];
#pragma unroll
            for (int mb = 0; mb < 2; mb++)
                Bf[mb] = *reinterpret_cast<const short8*>(
                    Eb + (mb * 16 + lm) * ESTR + kc * 32 + q * 8);
#pragma unroll
            for (int cb = 0; cb < 4; cb++)
#pragma unroll
                for (int mb = 0; mb < 2; mb++)
                    acc[cb][mb] = MFMA16(A[cb * 4 + kc], Bf[mb], acc[cb][mb]);
        }
    };

    loadQZ(q0, z0, 0);
    loadA(0);
    loadQZ(q1, z1, 1);

    for (int i = 0; i < 32; i += 2) {
        egen(q0, z0, Es[0]);
        __syncthreads();            // drains loadA(i) + loadQZ(i+1)
        loadQZ(q0, z0, i + 2);
        mainm(Es[0]);               // consumes A(i)
        loadA(i + 1);               // drained by next barrier, used right after

        egen(q1, z1, Es[1]);
        __syncthreads();            // drains loadA(i+1) + loadQZ(i+2)
        loadQZ(q1, z1, i + 3);
        mainm(Es[1]);               // consumes A(i+1)
        loadA(i + 2);
    }

    // epilogue: out = f + beta * acc  (D rows c = q*4+r, col m = lm)
    const float beta = *betap;
#pragma unroll
    for (int cb = 0; cb < 4; cb++) {
#pragma unroll
        for (int mb = 0; mb < 2; mb++) {
            const int c = w * 64 + cb * 16 + q * 4;
            const int m = m0 + mb * 16 + lm;
#pragma unroll
            for (int r = 0; r < 4; r++) {
                const size_t off = (size_t)(c + r) * N_ + m;
                o[off] = f[off] + beta * acc[cb][mb][r];
            }
        }
    }
}

// ---------------------------------------------------------------------------
extern "C" void kernel_launch(void* const* d_in, const int* in_sizes, int n_in,
                              void* d_out, int out_size, void* d_ws, size_t ws_size,
                              hipStream_t stream)
{
    const float* fL   = (const float*)d_in[0];
    const float* fU   = (const float*)d_in[1];
    const float* qL_w = (const float*)d_in[2];
    const float* qL_b = (const float*)d_in[3];
    const float* kU_w = (const float*)d_in[4];
    const float* kU_b = (const float*)d_in[5];
    const float* vU_w = (const float*)d_in[6];
    const float* vU_b = (const float*)d_in[7];
    const float* qU_w = (const float*)d_in[8];
    const float* qU_b = (const float*)d_in[9];
    const float* kL_w = (const float*)d_in[10];
    const float* kL_b = (const float*)d_in[11];
    const float* vL_w = (const float*)d_in[12];
    const float* vL_b = (const float*)d_in[13];
    const float* beta = (const float*)d_in[14];

    unsigned short* wsu  = (unsigned short*)d_ws;
    float*          wsf  = (float*)d_ws;
    float*          outf = (float*)d_out;

    fused_pre<<<dim3(128, 1, 4), 256, 0, stream>>>(
        fL, fU, qL_w, qL_b, kL_w, kL_b, vL_w, vL_b,
        qU_w, qU_b, kU_w, kU_b, vU_w, vU_b, wsu);

    zcalc<<<dim3(128, B_, 2), 256, 0, stream>>>(wsu, wsf);

    attn_gemm<<<dim3(128, 1, 4), 256, 0, stream>>>(
        fL, fU, beta, wsu, wsf, outf);
}